// Round 10
// baseline (104.204 us; speedup 1.0000x reference)
//
#include <hip/hip_runtime.h>
#include <hip/hip_bf16.h>
#include <math.h>

#define BB 8
#define SS 512
#define EE 128
#define HH 16
#define DKK 8

#define FMA4(ACC, S, W) do { (ACC).x += (S)*(W).x; (ACC).y += (S)*(W).y; \
                             (ACC).z += (S)*(W).z; (ACC).w += (S)*(W).w; } while(0)
#define DOT4(A, B) ((A).x*(B).x + (A).y*(B).y + (A).z*(B).z + (A).w*(B).w)

// ---------------------------------------------------------------------------
// Fused kernel: per-block (bh, q-half) — QKV head-slice GEMM + quantum head
// + attention, fully self-contained (no cross-block dependencies).
// grid 256 = (bh 0..127) x (q-half 0..1); block 512 = 8 waves; LDS 48KB.
//
// Phase A1: K/V for ALL 512 rows of this (b,h): x(512x128) @ W[:,h*8..h*8+8]
//   (4KB slice, L1-resident). 512 thr = 4 colgroups (K:0-3,4-7 / V:0-3,4-7)
//   x 128 rows; 4 rounds. Quantum head in-thread + one shfl_xor(1) pair
//   exchange. Results -> K_lds/V_lds [512][8].
// Phase A2: q for this q-half's 256 rows, same pattern (2 colgroups x 256
//   rows), written to q_lds [8][257] (padded, conflict-free).
// Phase B: R9-proven attention core: 8 waves split j 8-way (64 j each),
//   lane owns R=4 q rows; K/V broadcast ds_reads. q pre-scaled by
//   log2(e)/sqrt(8) -> exp2f (native v_exp_f32, no per-pair mul).
//   Single-pass softmax (scores bounded). Partials combined in the SAME
//   48KB LDS (stage is dead), normalized, written to hid (B,S,E).
// ---------------------------------------------------------------------------
__global__ __launch_bounds__(512, 2) void k_fused(
    const float* __restrict__ x,
    const float* __restrict__ Wq, const float* __restrict__ bq,
    const float* __restrict__ Wk, const float* __restrict__ bk,
    const float* __restrict__ Wv, const float* __restrict__ bv,
    const float* __restrict__ theta,
    float* __restrict__ hid)
{
    __shared__ float smem[12288];   // 48KB
    float* Kl = smem;               // [512][8]
    float* Vl = smem + 4096;        // [512][8]
    float* ql = smem + 8192;        // [8][257] padded

    const int t   = threadIdx.x;
    const int bh  = blockIdx.x >> 1;
    const int qhf = blockIdx.x & 1;
    const int b_  = bh >> 4;
    const int h   = bh & 15;
    const int q0  = qhf * 256;

    // ---------------- phase A1: K/V for all 512 rows ----------------
    {
        const int cg   = t & 3;          // 0,1 -> K ; 2,3 -> V
        const int mat  = cg >> 1;
        const int half = cg & 1;
        const int col0 = h * 8 + half * 4;
        const float* __restrict__ W = mat ? Wv : Wk;
        const float4 bias = *(const float4*)&(mat ? bv : bk)[col0];
        const float4 th   = *(const float4*)&theta[col0];
        float* outl = mat ? Vl : Kl;
        const int rbase = t >> 2;        // 0..127

        for (int round = 0; round < 4; ++round) {
            const int row = round * 128 + rbase;
            const float4* xr = (const float4*)(x + ((size_t)b_ * 512 + row) * 128);
            float4 acc = bias;
            #pragma unroll 4
            for (int k4 = 0; k4 < 32; ++k4) {
                const float4 xv = xr[k4];
                const float4 w0 = *(const float4*)&W[(k4 * 4 + 0) * 128 + col0];
                const float4 w1 = *(const float4*)&W[(k4 * 4 + 1) * 128 + col0];
                const float4 w2 = *(const float4*)&W[(k4 * 4 + 2) * 128 + col0];
                const float4 w3 = *(const float4*)&W[(k4 * 4 + 3) * 128 + col0];
                FMA4(acc, xv.x, w0); FMA4(acc, xv.y, w1);
                FMA4(acc, xv.z, w2); FMA4(acc, xv.w, w3);
            }
            float4 c;
            c.x = __cosf(acc.x + th.x);
            c.y = __cosf(acc.y + th.y);
            c.z = __cosf(acc.z + th.z);
            c.w = __cosf(acc.w + th.w);
            const float p0 = c.x;
            const float p1 = p0 * c.y;
            const float p2 = p1 * c.z;
            const float p3 = p2 * c.w;
            const float recv = __shfl_xor(p3, 1);   // partner half's 4-product
            float4 o;
            if (half == 0) {
                o.x = c.y * c.z * c.w * recv;  // wire 0: c1..c7
                o.y = p1;                       // wire 1: c0c1
                o.z = p2;
                o.w = p3;
            } else {
                o.x = recv * p0;                // wire 4: (c0..c3)c4
                o.y = recv * p1;
                o.z = recv * p2;
                o.w = recv * p3;
            }
            *(float4*)&outl[row * 8 + half * 4] = o;
        }
    }

    // ---------------- phase A2: q for this q-half's 256 rows ----------------
    {
        const int cg   = t & 1;
        const int row  = t >> 1;         // 0..255
        const int col0 = h * 8 + cg * 4;
        const float4 bias = *(const float4*)&bq[col0];
        const float4 th   = *(const float4*)&theta[col0];
        const float4* xr = (const float4*)(x + ((size_t)b_ * 512 + q0 + row) * 128);
        float4 acc = bias;
        #pragma unroll 4
        for (int k4 = 0; k4 < 32; ++k4) {
            const float4 xv = xr[k4];
            const float4 w0 = *(const float4*)&Wq[(k4 * 4 + 0) * 128 + col0];
            const float4 w1 = *(const float4*)&Wq[(k4 * 4 + 1) * 128 + col0];
            const float4 w2 = *(const float4*)&Wq[(k4 * 4 + 2) * 128 + col0];
            const float4 w3 = *(const float4*)&Wq[(k4 * 4 + 3) * 128 + col0];
            FMA4(acc, xv.x, w0); FMA4(acc, xv.y, w1);
            FMA4(acc, xv.z, w2); FMA4(acc, xv.w, w3);
        }
        float4 c;
        c.x = __cosf(acc.x + th.x);
        c.y = __cosf(acc.y + th.y);
        c.z = __cosf(acc.z + th.z);
        c.w = __cosf(acc.w + th.w);
        const float p0 = c.x;
        const float p1 = p0 * c.y;
        const float p2 = p1 * c.z;
        const float p3 = p2 * c.w;
        const float recv = __shfl_xor(p3, 1);
        float4 o;
        if (cg == 0) {
            o.x = c.y * c.z * c.w * recv;
            o.y = p1; o.z = p2; o.w = p3;
        } else {
            o.x = recv * p0; o.y = recv * p1;
            o.z = recv * p2; o.w = recv * p3;
        }
        ql[(cg * 4 + 0) * 257 + row] = o.x;
        ql[(cg * 4 + 1) * 257 + row] = o.y;
        ql[(cg * 4 + 2) * 257 + row] = o.z;
        ql[(cg * 4 + 3) * 257 + row] = o.w;
    }
    __syncthreads();

    // ---------------- phase B: attention ----------------
    const int L  = t & 63;
    const int wv = t >> 6;               // 0..7
    const float sc = 0.51012091944f;     // log2(e)/sqrt(8): exp2 softmax == exp softmax

    float4 qa[4], qb[4];
    #pragma unroll
    for (int r = 0; r < 4; ++r) {
        const int row = L + 64 * r;
        float4 a = make_float4(ql[0*257+row], ql[1*257+row], ql[2*257+row], ql[3*257+row]);
        float4 b = make_float4(ql[4*257+row], ql[5*257+row], ql[6*257+row], ql[7*257+row]);
        a.x *= sc; a.y *= sc; a.z *= sc; a.w *= sc;
        b.x *= sc; b.y *= sc; b.z *= sc; b.w *= sc;
        qa[r] = a; qb[r] = b;
    }

    float4 aA[4], aB[4];
    float  den[4];
    #pragma unroll
    for (int r = 0; r < 4; ++r) {
        aA[r] = make_float4(0.f, 0.f, 0.f, 0.f);
        aB[r] = make_float4(0.f, 0.f, 0.f, 0.f);
        den[r] = 0.f;
    }

    const float* kb = Kl + (wv * 64) * 8;   // this wave's 64 j rows
    const float* vb = Vl + (wv * 64) * 8;

    #pragma unroll 4
    for (int j = 0; j < 64; ++j) {
        const float4 k0 = *(const float4*)&kb[j * 8];
        const float4 k1 = *(const float4*)&kb[j * 8 + 4];
        const float4 v0 = *(const float4*)&vb[j * 8];
        const float4 v1 = *(const float4*)&vb[j * 8 + 4];
        #pragma unroll
        for (int r = 0; r < 4; ++r) {
            const float s = DOT4(qa[r], k0) + DOT4(qb[r], k1);
            const float e = exp2f(s);
            den[r] += e;
            FMA4(aA[r], e, v0);
            FMA4(aB[r], e, v1);
        }
    }
    __syncthreads();   // K/V/q stage dead; smem becomes partial buffer

    float4* part = (float4*)smem;        // [4][256][3] float4 = 48KB
    if (wv < 4) {
        #pragma unroll
        for (int r = 0; r < 4; ++r) {
            const int idx = (wv * 256 + L + 64 * r) * 3;
            part[idx]     = aA[r];
            part[idx + 1] = aB[r];
            part[idx + 2] = make_float4(den[r], 0.f, 0.f, 0.f);
        }
    }
    __syncthreads();
    if (wv >= 4) {
        #pragma unroll
        for (int r = 0; r < 4; ++r) {
            const int idx = ((wv - 4) * 256 + L + 64 * r) * 3;
            float4 pa = part[idx];
            float4 pb = part[idx + 1];
            float4 pd = part[idx + 2];
            pa.x += aA[r].x; pa.y += aA[r].y; pa.z += aA[r].z; pa.w += aA[r].w;
            pb.x += aB[r].x; pb.y += aB[r].y; pb.z += aB[r].z; pb.w += aB[r].w;
            pd.x += den[r];
            part[idx]     = pa;
            part[idx + 1] = pb;
            part[idx + 2] = pd;
        }
    }
    __syncthreads();

    if (t < 256) {
        float4 rA = make_float4(0.f, 0.f, 0.f, 0.f), rB = rA;
        float rd = 0.f;
        #pragma unroll
        for (int w = 0; w < 4; ++w) {
            const int idx = (w * 256 + t) * 3;
            const float4 a = part[idx];
            const float4 b = part[idx + 1];
            rA.x += a.x; rA.y += a.y; rA.z += a.z; rA.w += a.w;
            rB.x += b.x; rB.y += b.y; rB.z += b.z; rB.w += b.w;
            rd   += part[idx + 2].x;
        }
        const float inv = 1.0f / rd;
        rA.x *= inv; rA.y *= inv; rA.z *= inv; rA.w *= inv;
        rB.x *= inv; rB.y *= inv; rB.z *= inv; rB.w *= inv;
        float* o = hid + ((size_t)(b_ * 512) + q0 + t) * 128 + h * 8;
        ((float4*)o)[0] = rA;
        ((float4*)o)[1] = rB;
    }
}

// ---------------------------------------------------------------------------
// Output projection hid(4096x128, row-major) @ Wo(128x128) + bo.
// grid 256 x 256: 16 rows/block, LDS stage, per-lane tile 2 rows x 4 cols.
// ---------------------------------------------------------------------------
__global__ __launch_bounds__(256, 4) void k_out(
    const float* __restrict__ hid, const float* __restrict__ Wo,
    const float* __restrict__ bo, float* __restrict__ out)
{
    __shared__ float hs[16][128];
    const int t = threadIdx.x;
    const int row0 = blockIdx.x * 16;

    {
        const float4* hv = (const float4*)(hid + (size_t)row0 * 128);
        float4* hsv = (float4*)&hs[0][0];
        hsv[t]       = hv[t];
        hsv[t + 256] = hv[t + 256];
    }
    __syncthreads();

    const int cg   = t & 31;
    const int col0 = cg * 4;
    const int rg   = t >> 5;
    const int r0   = rg * 2;

    float4 acc0 = *(const float4*)&bo[col0];
    float4 acc1 = acc0;

    #pragma unroll 4
    for (int k4 = 0; k4 < 32; ++k4) {
        const float4 xa = ((const float4*)hs[r0 + 0])[k4];
        const float4 xb = ((const float4*)hs[r0 + 1])[k4];
        const float4 w0 = *(const float4*)&Wo[(k4 * 4 + 0) * 128 + col0];
        const float4 w1 = *(const float4*)&Wo[(k4 * 4 + 1) * 128 + col0];
        const float4 w2 = *(const float4*)&Wo[(k4 * 4 + 2) * 128 + col0];
        const float4 w3 = *(const float4*)&Wo[(k4 * 4 + 3) * 128 + col0];
        FMA4(acc0, xa.x, w0); FMA4(acc0, xa.y, w1);
        FMA4(acc0, xa.z, w2); FMA4(acc0, xa.w, w3);
        FMA4(acc1, xb.x, w0); FMA4(acc1, xb.y, w1);
        FMA4(acc1, xb.z, w2); FMA4(acc1, xb.w, w3);
    }

    *(float4*)&out[(size_t)(row0 + r0 + 0) * 128 + col0] = acc0;
    *(float4*)&out[(size_t)(row0 + r0 + 1) * 128 + col0] = acc1;
}

// ---------------------------------------------------------------------------
extern "C" void kernel_launch(void* const* d_in, const int* in_sizes, int n_in,
                              void* d_out, int out_size, void* d_ws, size_t ws_size,
                              hipStream_t stream)
{
    const float* x     = (const float*)d_in[0];
    const float* Wq    = (const float*)d_in[1];
    const float* bq    = (const float*)d_in[2];
    const float* Wk    = (const float*)d_in[3];
    const float* bk    = (const float*)d_in[4];
    const float* Wv    = (const float*)d_in[5];
    const float* bv    = (const float*)d_in[6];
    const float* Wo    = (const float*)d_in[7];
    const float* bo    = (const float*)d_in[8];
    const float* theta = (const float*)d_in[9];
    float* out = (float*)d_out;

    float* hid = (float*)d_ws;        // B*S*E = 524288 floats, row-major

    k_fused<<<256, 512, 0, stream>>>(x, Wq, bq, Wk, bk, Wv, bv, theta, hid);
    k_out  <<<256, 256, 0, stream>>>(hid, Wo, bo, out);
}

// Round 11
// 66.246 us; speedup vs baseline: 1.5730x; 1.5730x over previous
//
#include <hip/hip_runtime.h>
#include <hip/hip_bf16.h>
#include <math.h>

#define BB 8
#define SS 512
#define EE 128
#define HH 16
#define DKK 8

#define FMA4(ACC, S, W) do { (ACC).x += (S)*(W).x; (ACC).y += (S)*(W).y; \
                             (ACC).z += (S)*(W).z; (ACC).w += (S)*(W).w; } while(0)
#define ADD4(A, B) do { (A).x += (B).x; (A).y += (B).y; (A).z += (B).z; (A).w += (B).w; } while(0)
#define DOT4(A, B) ((A).x*(B).x + (A).y*(B).y + (A).z*(B).z + (A).w*(B).w)

// ---------------------------------------------------------------------------
// Kernel 1: QKV GEMM + bias + theta + quantum head (R9-proven).
// grid (256, 3); block 256 = 4 waves; per-lane tile 2 rows x 4 cols.
// x tile staged in LDS (8KB, broadcast b128 reads); W coalesced float4.
// Output layout (B, H, S, 8).
// ---------------------------------------------------------------------------
__global__ __launch_bounds__(256, 4) void k_qkvq(
    const float* __restrict__ x,
    const float* __restrict__ Wq, const float* __restrict__ bq,
    const float* __restrict__ Wk, const float* __restrict__ bk,
    const float* __restrict__ Wv, const float* __restrict__ bv,
    const float* __restrict__ theta,
    float* __restrict__ qh, float* __restrict__ kh, float* __restrict__ vh)
{
    __shared__ float xs[16][128];
    const int t = threadIdx.x;
    const int m = blockIdx.y;
    const int row0 = blockIdx.x * 16;

    {
        const float4* xv = (const float4*)(x + (size_t)row0 * 128);
        float4* xsv = (float4*)&xs[0][0];
        xsv[t]       = xv[t];
        xsv[t + 256] = xv[t + 256];
    }
    __syncthreads();

    const int cg   = t & 31;
    const int col0 = cg * 4;
    const int rg   = t >> 5;
    const int r0   = rg * 2;

    const float* __restrict__ W  = (m == 0) ? Wq : (m == 1) ? Wk : Wv;
    const float* __restrict__ bb = (m == 0) ? bq : (m == 1) ? bk : bv;
    float* __restrict__ outp     = (m == 0) ? qh : (m == 1) ? kh : vh;

    float4 acc0 = *(const float4*)&bb[col0];
    float4 acc1 = acc0;

    #pragma unroll 4
    for (int k4 = 0; k4 < 32; ++k4) {
        const float4 xa = ((const float4*)xs[r0 + 0])[k4];
        const float4 xb = ((const float4*)xs[r0 + 1])[k4];
        const float4 w0 = *(const float4*)&W[(k4 * 4 + 0) * 128 + col0];
        const float4 w1 = *(const float4*)&W[(k4 * 4 + 1) * 128 + col0];
        const float4 w2 = *(const float4*)&W[(k4 * 4 + 2) * 128 + col0];
        const float4 w3 = *(const float4*)&W[(k4 * 4 + 3) * 128 + col0];
        FMA4(acc0, xa.x, w0); FMA4(acc0, xa.y, w1);
        FMA4(acc0, xa.z, w2); FMA4(acc0, xa.w, w3);
        FMA4(acc1, xb.x, w0); FMA4(acc1, xb.y, w1);
        FMA4(acc1, xb.z, w2); FMA4(acc1, xb.w, w3);
    }

    const float4 th = *(const float4*)&theta[col0];
    const int h    = cg >> 1;
    const int half = cg & 1;

    float4 accs[2] = {acc0, acc1};
    #pragma unroll
    for (int r = 0; r < 2; ++r) {
        float4 c;
        c.x = __cosf(accs[r].x + th.x);
        c.y = __cosf(accs[r].y + th.y);
        c.z = __cosf(accs[r].z + th.z);
        c.w = __cosf(accs[r].w + th.w);
        const float p0 = c.x;
        const float p1 = p0 * c.y;
        const float p2 = p1 * c.z;
        const float p3 = p2 * c.w;
        const float recv = __shfl_xor(p3, 1);
        float4 o;
        if (half == 0) {
            o.x = c.y * c.z * c.w * recv;  // wire 0: c1..c7
            o.y = p1; o.z = p2; o.w = p3;  // wires 1-3: c0..cw
        } else {
            o.x = recv * p0;               // wires 4-7: (c0..c3)*(c4..cw)
            o.y = recv * p1;
            o.z = recv * p2;
            o.w = recv * p3;
        }
        const int g  = row0 + r0 + r;
        const int b_ = g >> 9;
        const int s  = g & 511;
        *(float4*)&outp[(((size_t)b_ * HH + h) * SS + s) * DKK + half * 4] = o;
    }
}

// ---------------------------------------------------------------------------
// Kernel 2: attention partials. grid 1024: bh = bid&127 (XCD-local),
// qhf = (bid>>7)&1 (q-half of 256 rows), jq = bid>>8 (j-quarter of 128).
// block 256 = 4 waves, 24KB LDS -> 4 blocks/CU = 4 waves/SIMD.
// Stage: this jq's 128 K/V rows (8KB). Wave wv = 32-j slice; lane owns
// R=4 q rows (L+64r). q pre-scaled by log2(e)/sqrt(8) -> exp2f.
// Single-pass softmax (bounded scores). 2-stage in-LDS combine (4 waves ->
// 2 slots -> 1), then un-normalized partial (8 sums + den) to ws.
// Partial layout: float4 gp[(bh*4+jq)*512 + q][3].
// ---------------------------------------------------------------------------
__global__ __launch_bounds__(256, 4) void k_attn(
    const float* __restrict__ qh, const float* __restrict__ kh,
    const float* __restrict__ vh, float* __restrict__ partg)
{
    __shared__ float4 smem[1536];     // 24KB: stage (512 f4) / combine (1536)

    const int t   = threadIdx.x;
    const int L   = t & 63;
    const int wv  = t >> 6;           // 0..3
    const int bh  = blockIdx.x & 127;
    const int qhf = (blockIdx.x >> 7) & 1;
    const int jq  = blockIdx.x >> 8;  // 0..3
    const int q0  = qhf * 256;

    // stage this j-quarter of K/V (128 rows x 2 f4 each)
    {
        const float4* kg = (const float4*)kh + (size_t)bh * 1024 + jq * 256;
        const float4* vg = (const float4*)vh + (size_t)bh * 1024 + jq * 256;
        smem[t]       = kg[t];
        smem[256 + t] = vg[t];
    }

    // lane's 4 q rows, pre-scaled so exp2f(s) == exp(q.k/sqrt(8))
    const float sc = 0.51012091944f;  // log2(e)/sqrt(8)
    float4 qa[4], qb[4];
    {
        const float4* qg = (const float4*)qh + ((size_t)bh * 512 + q0) * 2;
        #pragma unroll
        for (int r = 0; r < 4; ++r) {
            float4 a = qg[(L + 64 * r) * 2];
            float4 b = qg[(L + 64 * r) * 2 + 1];
            a.x *= sc; a.y *= sc; a.z *= sc; a.w *= sc;
            b.x *= sc; b.y *= sc; b.z *= sc; b.w *= sc;
            qa[r] = a; qb[r] = b;
        }
    }
    __syncthreads();

    float4 aA[4], aB[4];
    float  den[4];
    #pragma unroll
    for (int r = 0; r < 4; ++r) {
        aA[r] = make_float4(0.f, 0.f, 0.f, 0.f);
        aB[r] = make_float4(0.f, 0.f, 0.f, 0.f);
        den[r] = 0.f;
    }

    const float4* kbase = smem + wv * 64;        // 32 rows x 2 f4
    const float4* vbase = smem + 256 + wv * 64;

    #pragma unroll 4
    for (int j = 0; j < 32; ++j) {
        const float4 k0 = kbase[2 * j];
        const float4 k1 = kbase[2 * j + 1];
        const float4 v0 = vbase[2 * j];
        const float4 v1 = vbase[2 * j + 1];
        #pragma unroll
        for (int r = 0; r < 4; ++r) {
            const float s = DOT4(qa[r], k0) + DOT4(qb[r], k1);
            const float e = exp2f(s);
            den[r] += e;
            FMA4(aA[r], e, v0);
            FMA4(aB[r], e, v1);
        }
    }
    __syncthreads();    // stage reads complete; smem becomes combine buffer

    // 2-stage combine: slots [2][256][3] f4
    if (wv < 2) {
        #pragma unroll
        for (int r = 0; r < 4; ++r) {
            const int idx = (wv * 256 + L + 64 * r) * 3;
            smem[idx]     = aA[r];
            smem[idx + 1] = aB[r];
            smem[idx + 2] = make_float4(den[r], 0.f, 0.f, 0.f);
        }
    }
    __syncthreads();
    if (wv >= 2) {
        #pragma unroll
        for (int r = 0; r < 4; ++r) {
            const int idx = ((wv - 2) * 256 + L + 64 * r) * 3;
            float4 pa = smem[idx];
            float4 pb = smem[idx + 1];
            float4 pd = smem[idx + 2];
            ADD4(pa, aA[r]); ADD4(pb, aB[r]); pd.x += den[r];
            smem[idx]     = pa;
            smem[idx + 1] = pb;
            smem[idx + 2] = pd;
        }
    }
    __syncthreads();

    // final: un-normalized partial for this (bh, jq) -> global ws
    if (t < 256) {
        const int i0 = t * 3;
        const int i1 = (256 + t) * 3;
        float4 rA = smem[i0];     ADD4(rA, smem[i1]);
        float4 rB = smem[i0 + 1]; ADD4(rB, smem[i1 + 1]);
        const float rd = smem[i0 + 2].x + smem[i1 + 2].x;
        float4* gp = (float4*)partg + (((size_t)bh * 4 + jq) * 512 + q0 + t) * 3;
        gp[0] = rA;
        gp[1] = rB;
        gp[2] = make_float4(rd, 0.f, 0.f, 0.f);
    }
}

// ---------------------------------------------------------------------------
// Kernel 3: partial reduce (4 jq slots) + normalize + output projection.
// grid 512 x 256: 8 output rows/block (2 blocks/CU).
// Phase 1: t<128 owns (row rt, head h): sum 4 slots, normalize -> hs.
// Phase 2: GEMM hs(8x128) @ Wo + bo, 1 row x 4 cols per lane.
// ---------------------------------------------------------------------------
__global__ __launch_bounds__(256, 4) void k_out(
    const float* __restrict__ partg, const float* __restrict__ Wo,
    const float* __restrict__ bo, float* __restrict__ out)
{
    __shared__ float hs[8][128];
    const int t = threadIdx.x;
    const int row0 = blockIdx.x * 8;

    if (t < 128) {
        const int rt = t >> 4;
        const int h  = t & 15;
        const int g  = row0 + rt;
        const int b_ = g >> 9;
        const int s  = g & 511;
        const int bh = b_ * 16 + h;
        const float4* gp = (const float4*)partg;
        float4 rA = make_float4(0.f, 0.f, 0.f, 0.f), rB = rA;
        float rd = 0.f;
        #pragma unroll
        for (int jq = 0; jq < 4; ++jq) {
            const size_t base = (((size_t)bh * 4 + jq) * 512 + s) * 3;
            float4 a = gp[base];
            float4 b = gp[base + 1];
            ADD4(rA, a); ADD4(rB, b);
            rd += gp[base + 2].x;
        }
        const float inv = 1.0f / rd;
        rA.x *= inv; rA.y *= inv; rA.z *= inv; rA.w *= inv;
        rB.x *= inv; rB.y *= inv; rB.z *= inv; rB.w *= inv;
        *(float4*)&hs[rt][h * 8]     = rA;
        *(float4*)&hs[rt][h * 8 + 4] = rB;
    }
    __syncthreads();

    const int cg   = t & 31;
    const int col0 = cg * 4;
    const int rg   = t >> 5;          // 0..7: one row per lane-group

    float4 acc = *(const float4*)&bo[col0];

    #pragma unroll 4
    for (int k4 = 0; k4 < 32; ++k4) {
        const float4 xa = ((const float4*)hs[rg])[k4];
        const float4 w0 = *(const float4*)&Wo[(k4 * 4 + 0) * 128 + col0];
        const float4 w1 = *(const float4*)&Wo[(k4 * 4 + 1) * 128 + col0];
        const float4 w2 = *(const float4*)&Wo[(k4 * 4 + 2) * 128 + col0];
        const float4 w3 = *(const float4*)&Wo[(k4 * 4 + 3) * 128 + col0];
        FMA4(acc, xa.x, w0); FMA4(acc, xa.y, w1);
        FMA4(acc, xa.z, w2); FMA4(acc, xa.w, w3);
    }

    *(float4*)&out[(size_t)(row0 + rg) * 128 + col0] = acc;
}

// ---------------------------------------------------------------------------
extern "C" void kernel_launch(void* const* d_in, const int* in_sizes, int n_in,
                              void* d_out, int out_size, void* d_ws, size_t ws_size,
                              hipStream_t stream)
{
    const float* x     = (const float*)d_in[0];
    const float* Wq    = (const float*)d_in[1];
    const float* bq    = (const float*)d_in[2];
    const float* Wk    = (const float*)d_in[3];
    const float* bk    = (const float*)d_in[4];
    const float* Wv    = (const float*)d_in[5];
    const float* bv    = (const float*)d_in[6];
    const float* Wo    = (const float*)d_in[7];
    const float* bo    = (const float*)d_in[8];
    const float* theta = (const float*)d_in[9];
    float* out = (float*)d_out;

    float* ws    = (float*)d_ws;
    float* qh    = ws;                 // B*H*S*8 = 524288 floats each
    float* kh    = ws + 524288;
    float* vh    = ws + 1048576;
    float* partg = ws + 1572864;       // 128bh * 4jq * 512q * 12 floats = 12.6MB

    k_qkvq<<<dim3(256, 3), 256, 0, stream>>>(x, Wq, bq, Wk, bk, Wv, bv,
                                             theta, qh, kh, vh);
    k_attn<<<1024, 256, 0, stream>>>(qh, kh, vh, partg);
    k_out <<<512, 256, 0, stream>>>(partg, Wo, bo, out);
}